// Round 8
// baseline (916.659 us; speedup 1.0000x reference)
//
#include <hip/hip_runtime.h>

#define BATCH 8192
#define DIN 4096
#define DH 512

typedef float f32x4 __attribute__((ext_vector_type(4)));
typedef float f32x2 __attribute__((ext_vector_type(2)));
typedef short s16x8 __attribute__((ext_vector_type(8)));
typedef unsigned short u16x2 __attribute__((ext_vector_type(2)));
typedef unsigned short u16x4 __attribute__((ext_vector_type(4)));
typedef unsigned short u16x8 __attribute__((ext_vector_type(8)));

// round-to-nearest-even f32 -> bf16 bits
static __device__ __forceinline__ unsigned short f2bf(float f) {
  unsigned int u = __float_as_uint(f);
  u += 0x7FFFu + ((u >> 16) & 1u);
  return (unsigned short)(u >> 16);
}
static __device__ __forceinline__ float bf2f(unsigned short s) {
  return __uint_as_float(((unsigned int)s) << 16);
}

typedef const __attribute__((address_space(1))) unsigned int* gas_ptr;
typedef __attribute__((address_space(3))) unsigned int* las_ptr;
// async global->LDS, 16B per lane; LDS dest = wave-uniform base + lane*16
static __device__ __forceinline__ void gl_lds16(const unsigned short* g, unsigned short* l) {
  __builtin_amdgcn_global_load_lds((gas_ptr)g, (las_ptr)l, 16, 0, 0);
}

// ---------- elementwise f32 -> bf16 (big arrays; x) ----------
__global__ __launch_bounds__(256) void cast_bf16_k(
    const float* __restrict__ in, unsigned short* __restrict__ out)
{
  const int i = (blockIdx.x * 256 + threadIdx.x) * 4;
  f32x4 v = *(const f32x4*)(in + i);
  u16x4 p = { f2bf(v[0]), f2bf(v[1]), f2bf(v[2]), f2bf(v[3]) };
  *(u16x4*)(out + i) = p;
}

// ---------- transpose tile body: in f32 [R][C] -> out bf16 [(row_off+c)][r] ----------
static __device__ __forceinline__ void transpose_body(
    const float* __restrict__ in, int C,
    unsigned short* __restrict__ out, int ldo, int row_off,
    int bx, int by, float (*tl)[33])
{
  const int tid = threadIdx.x;
  const int tx = tid & 31, ty = tid >> 5;
  const int c0 = bx * 32, r0 = by * 32;
#pragma unroll
  for (int i = 0; i < 4; i++)
    tl[ty + 8 * i][tx] = in[(size_t)(r0 + ty + 8 * i) * C + c0 + tx];
  __syncthreads();
#pragma unroll
  for (int i = 0; i < 4; i++)
    out[(size_t)(row_off + c0 + ty + 8 * i) * ldo + r0 + tx] = f2bf(tl[tx][ty + 8 * i]);
}

// ---------- merged small prep: cast_h | cast_A | T(W1) | T(base_B) | zfill | T(W2) ----------
__global__ __launch_bounds__(256) void prep_small_k(
    const float* __restrict__ h, unsigned short* __restrict__ hbf,
    const float* __restrict__ base_A, unsigned short* __restrict__ Abf,
    const float* __restrict__ W1, const float* __restrict__ base_B,
    unsigned short* __restrict__ BTcat,
    const float* __restrict__ W2, unsigned short* __restrict__ W2T)
{
  __shared__ float tl[32][33];
  const int b = blockIdx.x;
  const int tid = threadIdx.x;
  const int KC = DIN + DH;
  if (b < 4096) {
    const int i = (b * 256 + tid) * 4;
    f32x4 v = *(const f32x4*)(h + i);
    u16x4 p = { f2bf(v[0]), f2bf(v[1]), f2bf(v[2]), f2bf(v[3]) };
    *(u16x4*)(hbf + i) = p;
  } else if (b < 4352) {
    const int i = ((b - 4096) * 256 + tid) * 4;
    f32x4 v = *(const f32x4*)(base_A + i);
    u16x4 p = { f2bf(v[0]), f2bf(v[1]), f2bf(v[2]), f2bf(v[3]) };
    *(u16x4*)(Abf + i) = p;
  } else if (b < 6656) {
    const int bb = b - 4352;                       // W1 [4608][512]
    transpose_body(W1, DH, BTcat, KC, 0, bb & 15, bb >> 4, tl);
  } else if (b < 8704) {
    const int bb = b - 6656;                       // base_B [4096][512]
    transpose_body(base_B, DH, BTcat, KC, DH, bb & 15, bb >> 4, tl);
  } else if (b < 8832) {
    const int gid = (b - 8704) * 256 + tid;        // zero pad corner 512x512
    const int row = gid >> 6, c = (gid & 63) * 8;
    u16x8 z = { 0, 0, 0, 0, 0, 0, 0, 0 };
    *(u16x8*)(BTcat + (size_t)(DH + row) * KC + DIN + c) = z;
  } else {
    const int bb = b - 8832;                       // W2 [512][1536]
    transpose_body(W2, 3 * DH, W2T, DH, 0, bb % 48, bb / 48, tl);
  }
}

// ---------------------------------------------------------------------------
// Wide-N GEMM engine: 128x256 tile, BK=32, 512 threads = 8 waves (2M x 4N,
// wave tile 64x64, 4x4 frags of 16x16x32). Double-buffered LDS (48 KB ->
// 3 blocks/CU), 2-phase: STAGE(next) -> ds_read/MFMA -> vmcnt(0)+barrier.
// Swizzle (zero-conflict, verified r7): stage source chunk scol =
// ((l&3)^((l>>3)&3))*8 ; read chunk fk = ((l>>4)^((l>>1)&3))*8.
// Staging: 24 x 16-row chunks (8 A + 16 B), 3 chunks per wave.
// EPI: 1 = +bias then scale transforms -> C0; 2 = raw -> C0;
//      3 = split: col<512 -> C0 +bias ; col>=512 -> C1 raw (both ld 512).
// ---------------------------------------------------------------------------
template<int EPI>
static __device__ __forceinline__ void gemm3_engine(
    const unsigned short* __restrict__ A0, int lda0, int K0,
    const unsigned short* __restrict__ A1, int lda1,
    const unsigned short* __restrict__ BT, int ldb,
    unsigned short* __restrict__ C0, int ldc,
    unsigned short* __restrict__ C1,
    const float* __restrict__ bias,
    const float* __restrict__ base_tau,
    int mb, int nb, int K, char* smem)
{
  unsigned short* As = (unsigned short*)smem;            // [2][128][32]
  unsigned short* Bs = (unsigned short*)(smem + 16384);  // [2][256][32]

  const int tid = threadIdx.x;
  const int lane = tid & 63;
  const int wid = tid >> 6;        // 0..7
  const int wm = (wid >> 2) * 64;
  const int wn = (wid & 3) * 64;
  const int srow = lane >> 2;                                // staging row in chunk
  const int scol = ((lane & 3) ^ ((lane >> 3) & 3)) * 8;     // swizzled source chunk
  const int fr = lane & 15;                                  // fragment row/col
  const int fk = ((lane >> 4) ^ ((lane >> 1) & 3)) * 8;      // swizzled read chunk
  const int NT = K / 32;

  f32x4 acc[4][4];
#pragma unroll
  for (int i = 0; i < 4; i++)
#pragma unroll
    for (int j = 0; j < 4; j++)
      acc[i][j] = (f32x4){ 0.f, 0.f, 0.f, 0.f };

  // stage K-tile t into buffer buf: 3 chunks per wave (wave-uniform branch)
  auto STAGE = [&](int buf, int t) {
    const int k0 = t * 32;
    const bool s0 = (k0 < K0);
    const unsigned short* Ab = s0 ? A0 : A1;
    const int ld = s0 ? lda0 : lda1;
    const int ko = (s0 ? k0 : k0 - K0) + scol;
#pragma unroll
    for (int j = 0; j < 3; j++) {
      const int c = wid * 3 + j;          // 0..23, uniform per wave
      if (c < 8) {                        // A chunk: rows 16c..16c+15
        const int r = c * 16 + srow;
        gl_lds16(Ab + (size_t)(mb + r) * ld + ko, As + buf * 4096 + c * 512);
      } else {                            // B chunk
        const int r = (c - 8) * 16 + srow;
        gl_lds16(BT + (size_t)(nb + r) * ldb + k0 + scol, Bs + buf * 8192 + (c - 8) * 512);
      }
    }
  };

  STAGE(0, 0);
  asm volatile("s_waitcnt vmcnt(0)" ::: "memory");
  __builtin_amdgcn_s_barrier();

  int buf = 0;
  for (int t = 0; t < NT; t++) {
    if (t + 1 < NT) STAGE(buf ^ 1, t + 1);   // issue next-tile loads first

    const unsigned short* ar = As + buf * 4096;
    const unsigned short* br = Bs + buf * 8192;
    s16x8 af[4], bv[4];
#pragma unroll
    for (int mi = 0; mi < 4; mi++)
      af[mi] = *(const s16x8*)(ar + (wm + mi * 16 + fr) * 32 + fk);
#pragma unroll
    for (int ni = 0; ni < 4; ni++)
      bv[ni] = *(const s16x8*)(br + (wn + ni * 16 + fr) * 32 + fk);

    // reads complete before this wave's barrier (buffer-reuse safety),
    // MFMAs pinned after the wait (rule #18).
    asm volatile("s_waitcnt lgkmcnt(0)" ::: "memory");
    __builtin_amdgcn_sched_barrier(0);

#pragma unroll
    for (int mi = 0; mi < 4; mi++)
#pragma unroll
      for (int ni = 0; ni < 4; ni++)
        acc[mi][ni] = __builtin_amdgcn_mfma_f32_16x16x32_bf16(
            af[mi], bv[ni], acc[mi][ni], 0, 0, 0);

    // next-tile loads must land before they're read next period
    asm volatile("s_waitcnt vmcnt(0)" ::: "memory");
    __builtin_amdgcn_s_barrier();
    buf ^= 1;
  }

  const int rb = (lane >> 4) * 4;
#pragma unroll
  for (int mi = 0; mi < 4; mi++) {
#pragma unroll
    for (int ni = 0; ni < 4; ni++) {
#pragma unroll
      for (int r = 0; r < 4; r++) {
        const int row = mb + wm + mi * 16 + rb + r;
        const int col = nb + wn + ni * 16 + fr;
        float v = acc[mi][ni][r];
        if (EPI == 3) {
          if (col < DH) C0[(size_t)row * DH + col] = f2bf(v + bias[col]);
          else          C1[(size_t)row * DH + (col - DH)] = f2bf(v);
        } else if (EPI == 2) {
          C0[(size_t)row * ldc + col] = f2bf(v);
        } else if (EPI == 1) {
          v += bias[col];
          if ((col >> 9) == 0) {
            const float s = 1.0f / (1.0f + expf(-v));
            v = 1.0f / (base_tau[col & (DH - 1)] * 2.0f * s + 1e-8f);  // tau_inv
          } else {
            v = 1.0f + 0.5f * tanhf(v);                                 // A_row/B_col
          }
          C0[(size_t)row * ldc + col] = f2bf(v);
        }
      }
    }
  }
}

// ---- fused G1|GB: [x|h] @ [W1 | base_B~] -> pre1, rawB. XCD-swizzled ----
// grid 256 = (M/128=64) x (N/256=4); cpx=32 -> each XCD: one N-column half.
__global__ __launch_bounds__(512, 6) void fused_gemm_k(
    const unsigned short* __restrict__ xbf,
    const unsigned short* __restrict__ hbf,
    const unsigned short* __restrict__ BTcat,
    unsigned short* __restrict__ pre1,
    unsigned short* __restrict__ rawB,
    const float* __restrict__ b1)
{
  __shared__ __align__(16) char smem[49152];
  const int cpx = gridDim.x >> 3;                             // 256/8 = 32
  const int virt = (blockIdx.x & 7) * cpx + (blockIdx.x >> 3);
  const int mb = (virt & 63) * 128;
  const int nb = (virt >> 6) * 256;
  gemm3_engine<3>(xbf, DIN, DIN, hbf, DH, BTcat, DIN + DH,
                  pre1, DH, rawB, b1, nullptr, mb, nb, DIN + DH, smem);
}

// ---- merged tail: blocks [0,384) G2 scales; [384,512) GA rawA ----
__global__ __launch_bounds__(512, 6) void tail_gemm_k(
    const unsigned short* __restrict__ hbf,
    const unsigned short* __restrict__ Abf,
    const unsigned short* __restrict__ tbf,
    const unsigned short* __restrict__ W2T,
    unsigned short* __restrict__ rawA,
    unsigned short* __restrict__ scales,
    const float* __restrict__ b2,
    const float* __restrict__ base_tau)
{
  __shared__ __align__(16) char smem[49152];
  const int b = blockIdx.x;
  if (b < 384) {
    const int mb = (b & 63) * 128, nb = (b >> 6) * 256;      // N = 6*256 = 1536
    gemm3_engine<1>(tbf, DH, DH, nullptr, 0, W2T, DH,
                    scales, 3 * DH, nullptr, b2, base_tau, mb, nb, DH, smem);
  } else {
    const int bb = b - 384;
    const int mb = (bb & 63) * 128, nb = (bb >> 6) * 256;    // N = 2*256 = 512
    gemm3_engine<2>(hbf, DH, DH, nullptr, 0, Abf, DH,
                    rawA, DH, nullptr, nullptr, nullptr, mb, nb, DH, smem);
  }
}

// ---------- block-wide sum over 256 threads (4 waves) ----------
__device__ __forceinline__ float block_sum256(float v, float* red) {
#pragma unroll
  for (int m = 32; m >= 1; m >>= 1) v += __shfl_xor(v, m, 64);
  __syncthreads();
  if ((threadIdx.x & 63) == 0) red[threadIdx.x >> 6] = v;
  __syncthreads();
  return red[0] + red[1] + red[2] + red[3];
}

// ---------- t = bf16(gelu_exact(LN(pre1))) ----------
__global__ __launch_bounds__(256) void ln_gelu_k(
    const unsigned short* __restrict__ pre,
    const float* __restrict__ g, const float* __restrict__ b,
    unsigned short* __restrict__ t)
{
  __shared__ float red[4];
  const int row = blockIdx.x;
  const int c = threadIdx.x * 2;
  const size_t ro = (size_t)row * DH;
  u16x2 raw = *(const u16x2*)(pre + ro + c);
  const float v0 = bf2f(raw[0]), v1 = bf2f(raw[1]);
  const float mu = block_sum256(v0 + v1, red) * (1.0f / DH);
  const float d0 = v0 - mu, d1 = v1 - mu;
  const float var = block_sum256(d0 * d0 + d1 * d1, red) * (1.0f / DH);
  const float inv = rsqrtf(var + 1e-5f);
  const float y0 = d0 * inv * g[c] + b[c];
  const float y1 = d1 * inv * g[c + 1] + b[c + 1];
  u16x2 o = { f2bf(0.5f * y0 * (1.0f + erff(y0 * 0.70710678118f))),
              f2bf(0.5f * y1 * (1.0f + erff(y1 * 0.70710678118f))) };
  *(u16x2*)(t + ro + c) = o;
}

// ---------- new_h = LN(h + dt*(-h*tauinv + tanh(rawA*arow + rawB*bcol))) ----------
__global__ __launch_bounds__(256) void final_k(
    const float* __restrict__ h,
    const unsigned short* __restrict__ rawA,
    const unsigned short* __restrict__ rawB,
    const unsigned short* __restrict__ scales,
    const float* __restrict__ hn_g, const float* __restrict__ hn_b,
    float* __restrict__ out)
{
  __shared__ float red[4];
  const int row = blockIdx.x;
  const int c = threadIdx.x * 2;
  const size_t ro = (size_t)row * DH;
  f32x2 hv = *(const f32x2*)(h + ro + c);
  u16x2 ra = *(const u16x2*)(rawA + ro + c);
  u16x2 rb = *(const u16x2*)(rawB + ro + c);
  const unsigned short* sc = scales + (size_t)row * (3 * DH);
  u16x2 ti  = *(const u16x2*)(sc + c);
  u16x2 arw = *(const u16x2*)(sc + DH + c);
  u16x2 bcl = *(const u16x2*)(sc + 2 * DH + c);
  const float u0 = hv[0] + 0.1f * (-hv[0] * bf2f(ti[0])
                 + tanhf(bf2f(ra[0]) * bf2f(arw[0]) + bf2f(rb[0]) * bf2f(bcl[0])));
  const float u1 = hv[1] + 0.1f * (-hv[1] * bf2f(ti[1])
                 + tanhf(bf2f(ra[1]) * bf2f(arw[1]) + bf2f(rb[1]) * bf2f(bcl[1])));
  const float mu = block_sum256(u0 + u1, red) * (1.0f / DH);
  const float d0 = u0 - mu, d1 = u1 - mu;
  const float var = block_sum256(d0 * d0 + d1 * d1, red) * (1.0f / DH);
  const float inv = rsqrtf(var + 1e-5f);
  f32x2 o = { d0 * inv * hn_g[c] + hn_b[c],
              d1 * inv * hn_g[c + 1] + hn_b[c + 1] };
  *(f32x2*)(out + ro + c) = o;
}

extern "C" void kernel_launch(void* const* d_in, const int* in_sizes, int n_in,
                              void* d_out, int out_size, void* d_ws, size_t ws_size,
                              hipStream_t stream)
{
  const float* x        = (const float*)d_in[0];
  const float* h        = (const float*)d_in[1];
  const float* W1       = (const float*)d_in[2];   // [4608][512]
  const float* b1       = (const float*)d_in[3];
  const float* ln1_g    = (const float*)d_in[4];
  const float* ln1_b    = (const float*)d_in[5];
  const float* W2       = (const float*)d_in[6];   // [512][1536]
  const float* b2       = (const float*)d_in[7];
  const float* base_tau = (const float*)d_in[8];
  const float* base_A   = (const float*)d_in[9];   // [512][512]
  const float* base_B   = (const float*)d_in[10];  // [4096][512]
  const float* hn_g     = (const float*)d_in[11];
  const float* hn_b     = (const float*)d_in[12];

  char* w = (char*)d_ws;
  // ws layout (bytes), total 128,974,848 (== proven-safe footprint):
  unsigned short* xbf    = (unsigned short*)(w);               // [8192][4096] 67,108,864
  unsigned short* hbf    = (unsigned short*)(w + 67108864);    // [8192][512]   8,388,608
  unsigned short* BTcat  = (unsigned short*)(w + 75497472);    // [1024][4608]  9,437,184
  unsigned short* tbf    = (unsigned short*)(w + 75497472);    // ALIAS over BTcat (dead after fused GEMM)
  unsigned short* W2T    = (unsigned short*)(w + 84934656);    // [1536][512]   1,572,864
  unsigned short* Abf    = (unsigned short*)(w + 86507520);    // [512][512]      524,288
  unsigned short* pre1   = (unsigned short*)(w + 87031808);    // [8192][512]   8,388,608
  unsigned short* rawA   = (unsigned short*)(w + 87031808);    // ALIAS over pre1 (dead after ln_gelu)
  unsigned short* rawB   = (unsigned short*)(w + 95420416);    // [8192][512]   8,388,608
  unsigned short* scales = (unsigned short*)(w + 103809024);   // [8192][1536] 25,165,824

  // ---- prep: big x cast + merged small prep ----
  cast_bf16_k<<<DIN * BATCH / 1024, 256, 0, stream>>>(x, xbf);
  prep_small_k<<<9600, 256, 0, stream>>>(h, hbf, base_A, Abf, W1, base_B, BTcat, W2, W2T);

  // ---- fused G1|GB -> pre1, rawB ----
  fused_gemm_k<<<256, 512, 0, stream>>>(xbf, hbf, BTcat, pre1, rawB, b1);
  // ---- t = gelu(LN(pre1)) -> tbf ----
  ln_gelu_k<<<BATCH, 256, 0, stream>>>(pre1, ln1_g, ln1_b, tbf);
  // ---- merged tail: scales = transforms(t @ W2 + b2); rawA = h @ base_A^T ----
  tail_gemm_k<<<512, 512, 0, stream>>>(hbf, Abf, tbf, W2T, rawA, scales, b2, base_tau);
  // ---- final: dhdt + LN -> f32 out ----
  final_k<<<BATCH, 256, 0, stream>>>(h, rawA, rawB, scales, hn_g, hn_b, (float*)d_out);
}

// Round 9
// 215.849 us; speedup vs baseline: 4.2468x; 4.2468x over previous
//
#include <hip/hip_runtime.h>

#define BATCH 8192
#define DIN 4096
#define DH 512

typedef float f32x4 __attribute__((ext_vector_type(4)));
typedef float f32x2 __attribute__((ext_vector_type(2)));
typedef short s16x8 __attribute__((ext_vector_type(8)));
typedef unsigned short u16x2 __attribute__((ext_vector_type(2)));
typedef unsigned short u16x4 __attribute__((ext_vector_type(4)));
typedef unsigned short u16x8 __attribute__((ext_vector_type(8)));

// round-to-nearest-even f32 -> bf16 bits
static __device__ __forceinline__ unsigned short f2bf(float f) {
  unsigned int u = __float_as_uint(f);
  u += 0x7FFFu + ((u >> 16) & 1u);
  return (unsigned short)(u >> 16);
}
static __device__ __forceinline__ float bf2f(unsigned short s) {
  return __uint_as_float(((unsigned int)s) << 16);
}

typedef const __attribute__((address_space(1))) unsigned int* gas_ptr;
typedef __attribute__((address_space(3))) unsigned int* las_ptr;
// async global->LDS, 16B per lane; LDS dest = wave-uniform base + lane*16
static __device__ __forceinline__ void gl_lds16(const unsigned short* g, unsigned short* l) {
  __builtin_amdgcn_global_load_lds((gas_ptr)g, (las_ptr)l, 16, 0, 0);
}

// ---------- transpose tile body: in f32 [R][C] -> out bf16 [(row_off+c)][r] ----------
static __device__ __forceinline__ void transpose_body(
    const float* __restrict__ in, int C,
    unsigned short* __restrict__ out, int ldo, int row_off,
    int bx, int by, float (*tl)[33])
{
  const int tid = threadIdx.x;
  const int tx = tid & 31, ty = tid >> 5;
  const int c0 = bx * 32, r0 = by * 32;
#pragma unroll
  for (int i = 0; i < 4; i++)
    tl[ty + 8 * i][tx] = in[(size_t)(r0 + ty + 8 * i) * C + c0 + tx];
  __syncthreads();
#pragma unroll
  for (int i = 0; i < 4; i++)
    out[(size_t)(row_off + c0 + ty + 8 * i) * ldo + r0 + tx] = f2bf(tl[tx][ty + 8 * i]);
}

// ---------- single prep dispatch: cast x | cast h | cast A | T(W1) | T(base_B) | zfill | T(W2) ----------
// ranges: [0,32768) cast x; [32768,36864) cast h; [36864,37120) cast A;
// [37120,39424) T W1; [39424,41472) T base_B; [41472,41600) zfill; [41600,42368) T W2
__global__ __launch_bounds__(256) void prep_all_k(
    const float* __restrict__ x, unsigned short* __restrict__ xbf,
    const float* __restrict__ h, unsigned short* __restrict__ hbf,
    const float* __restrict__ base_A, unsigned short* __restrict__ Abf,
    const float* __restrict__ W1, const float* __restrict__ base_B,
    unsigned short* __restrict__ BTcat,
    const float* __restrict__ W2, unsigned short* __restrict__ W2T)
{
  __shared__ float tl[32][33];
  const int b = blockIdx.x;
  const int tid = threadIdx.x;
  const int KC = DIN + DH;
  if (b < 32768) {
    const int i = (b * 256 + tid) * 4;
    f32x4 v = *(const f32x4*)(x + i);
    u16x4 p = { f2bf(v[0]), f2bf(v[1]), f2bf(v[2]), f2bf(v[3]) };
    *(u16x4*)(xbf + i) = p;
  } else if (b < 36864) {
    const int i = ((b - 32768) * 256 + tid) * 4;
    f32x4 v = *(const f32x4*)(h + i);
    u16x4 p = { f2bf(v[0]), f2bf(v[1]), f2bf(v[2]), f2bf(v[3]) };
    *(u16x4*)(hbf + i) = p;
  } else if (b < 37120) {
    const int i = ((b - 36864) * 256 + tid) * 4;
    f32x4 v = *(const f32x4*)(base_A + i);
    u16x4 p = { f2bf(v[0]), f2bf(v[1]), f2bf(v[2]), f2bf(v[3]) };
    *(u16x4*)(Abf + i) = p;
  } else if (b < 39424) {
    const int bb = b - 37120;                      // W1 [4608][512]
    transpose_body(W1, DH, BTcat, KC, 0, bb & 15, bb >> 4, tl);
  } else if (b < 41472) {
    const int bb = b - 39424;                      // base_B [4096][512]
    transpose_body(base_B, DH, BTcat, KC, DH, bb & 15, bb >> 4, tl);
  } else if (b < 41600) {
    const int gid = (b - 41472) * 256 + tid;       // zero pad corner 512x512
    const int row = gid >> 6, c = (gid & 63) * 8;
    u16x8 z = { 0, 0, 0, 0, 0, 0, 0, 0 };
    *(u16x8*)(BTcat + (size_t)(DH + row) * KC + DIN + c) = z;
  } else {
    const int bb = b - 41600;                      // W2 [512][1536]
    transpose_body(W2, 3 * DH, W2T, DH, 0, bb % 48, bb / 48, tl);
  }
}

// ---------------------------------------------------------------------------
// Dual-K-stream GEMM engine (r7, measured 722 TF / 0 conflicts): 128x128 tile,
// 512 threads = 8 waves in 2 groups. Group g computes K-tiles 2t+g; each
// group's 4 waves own 64x64 sub-tiles (4x4 frags of 16x16x32). Per-group
// double-buffered LDS (64KB total), 2-phase: STAGE(next) -> ds_read/MFMA ->
// vmcnt(0)+barrier. Swizzle: physical 16B chunk = logical ^ ((row>>1)&3);
// write side scol = ((l&3)^((l>>3)&3))*8, read side fk = ((l>>4)^((l>>1)&3))*8.
// Epilogue: group 1 dumps f32 accs to LDS, group 0 adds and writes C.
// EPI: 1 = +bias then scale transforms -> C0; 2 = raw -> C0;
//      3 = split: col<512 -> C0 +bias ; col>=512 -> C1 raw (both ld 512).
// ---------------------------------------------------------------------------
template<int EPI>
static __device__ __forceinline__ void gemm2_engine(
    const unsigned short* __restrict__ A0, int lda0, int K0,
    const unsigned short* __restrict__ A1, int lda1,
    const unsigned short* __restrict__ BT, int ldb,
    unsigned short* __restrict__ C0, int ldc,
    unsigned short* __restrict__ C1,
    const float* __restrict__ bias,
    const float* __restrict__ base_tau,
    int mb, int nb, int K, char* smem)
{
  unsigned short* As = (unsigned short*)smem;             // [grp][buf][4096]
  unsigned short* Bs = (unsigned short*)(smem + 32768);   // [grp][buf][4096]
  float* red = (float*)smem;                              // 64KB reduction (reuse)

  const int tid = threadIdx.x;
  const int lane = tid & 63;
  const int wid = tid >> 6;        // 0..7
  const int grp = wid >> 2;        // 0 = even K-tiles, 1 = odd
  const int wg  = wid & 3;         // wave within group
  const int wm = (wg >> 1) * 64;
  const int wn = (wg & 1) * 64;
  const int srow = lane >> 2;                                // staging row in 16-chunk
  const int scol = ((lane & 3) ^ ((lane >> 3) & 3)) * 8;     // swizzled source chunk
  const int fr = lane & 15;                                  // fragment row/col
  const int fk = ((lane >> 4) ^ ((lane >> 1) & 3)) * 8;      // swizzled read chunk
  const int NT2 = K / 64;          // periods (2 K-tiles consumed per period)

  f32x4 acc[4][4];
#pragma unroll
  for (int i = 0; i < 4; i++)
#pragma unroll
    for (int j = 0; j < 4; j++)
      acc[i][j] = (f32x4){ 0.f, 0.f, 0.f, 0.f };

  // stage this group's tile for period 'per' into buffer buf (4 gl_lds/wave)
  auto STAGE = [&](int buf, int per) {
    const int tk = 2 * per + grp;
    const int k0 = tk * 32;
    const bool s0 = (k0 < K0);
    const unsigned short* Ab = s0 ? A0 : A1;
    const int ld = s0 ? lda0 : lda1;
    const int ko = (s0 ? k0 : k0 - K0) + scol;
    unsigned short* ab = As + (grp * 2 + buf) * 4096 + (32 * wg) * 32;
    unsigned short* bb = Bs + (grp * 2 + buf) * 4096 + (32 * wg) * 32;
#pragma unroll
    for (int c = 0; c < 2; c++) {
      const int r = 32 * wg + c * 16 + srow;
      gl_lds16(Ab + (size_t)(mb + r) * ld + ko, ab + c * 16 * 32);
      gl_lds16(BT + (size_t)(nb + r) * ldb + k0 + scol, bb + c * 16 * 32);
    }
  };

  STAGE(0, 0);
  asm volatile("s_waitcnt vmcnt(0)" ::: "memory");
  __builtin_amdgcn_s_barrier();

  int buf = 0;
  for (int t = 0; t < NT2; t++) {
    if (t + 1 < NT2) STAGE(buf ^ 1, t + 1);   // issue next-period loads first

    const unsigned short* ar = As + (grp * 2 + buf) * 4096;
    const unsigned short* br = Bs + (grp * 2 + buf) * 4096;
    s16x8 af[4], bv[4];
#pragma unroll
    for (int mi = 0; mi < 4; mi++)
      af[mi] = *(const s16x8*)(ar + (wm + mi * 16 + fr) * 32 + fk);
#pragma unroll
    for (int ni = 0; ni < 4; ni++)
      bv[ni] = *(const s16x8*)(br + (wn + ni * 16 + fr) * 32 + fk);

    // reads complete before this wave's barrier (buffer-reuse safety),
    // MFMAs pinned after the wait (rule #18).
    asm volatile("s_waitcnt lgkmcnt(0)" ::: "memory");
    __builtin_amdgcn_sched_barrier(0);

#pragma unroll
    for (int mi = 0; mi < 4; mi++)
#pragma unroll
      for (int ni = 0; ni < 4; ni++)
        acc[mi][ni] = __builtin_amdgcn_mfma_f32_16x16x32_bf16(
            af[mi], bv[ni], acc[mi][ni], 0, 0, 0);

    // next-period loads (issued ~full period ago) must land before reuse
    asm volatile("s_waitcnt vmcnt(0)" ::: "memory");
    __builtin_amdgcn_s_barrier();
    buf ^= 1;
  }

  // ---- cross-group reduction: group1 -> LDS, group0 adds ----
  if (grp == 1) {
#pragma unroll
    for (int mi = 0; mi < 4; mi++)
#pragma unroll
      for (int ni = 0; ni < 4; ni++)
        *(f32x4*)(red + (((wg * 4 + mi) * 4 + ni) * 64 + lane) * 4) = acc[mi][ni];
  }
  __syncthreads();
  if (grp != 0) return;

  const int rb = (lane >> 4) * 4;
#pragma unroll
  for (int mi = 0; mi < 4; mi++) {
#pragma unroll
    for (int ni = 0; ni < 4; ni++) {
      f32x4 o = *(const f32x4*)(red + (((wg * 4 + mi) * 4 + ni) * 64 + lane) * 4);
      acc[mi][ni] += o;
#pragma unroll
      for (int r = 0; r < 4; r++) {
        const int row = mb + wm + mi * 16 + rb + r;
        const int col = nb + wn + ni * 16 + fr;
        float v = acc[mi][ni][r];
        if (EPI == 3) {
          if (col < DH) C0[(size_t)row * DH + col] = f2bf(v + bias[col]);
          else          C1[(size_t)row * DH + (col - DH)] = f2bf(v);
        } else if (EPI == 2) {
          C0[(size_t)row * ldc + col] = f2bf(v);
        } else if (EPI == 1) {
          v += bias[col];
          if ((col >> 9) == 0) {
            const float s = 1.0f / (1.0f + expf(-v));
            v = 1.0f / (base_tau[col & (DH - 1)] * 2.0f * s + 1e-8f);  // tau_inv
          } else {
            v = 1.0f + 0.5f * tanhf(v);                                 // A_row/B_col
          }
          C0[(size_t)row * ldc + col] = f2bf(v);
        }
      }
    }
  }
}

// ---- fused G1|GB: [x|h] @ [W1 | base_B~] -> pre1, rawB. XCD-swizzled ----
__global__ __launch_bounds__(512, 4) void fused_gemm_k(
    const unsigned short* __restrict__ xbf,
    const unsigned short* __restrict__ hbf,
    const unsigned short* __restrict__ BTcat,
    unsigned short* __restrict__ pre1,
    unsigned short* __restrict__ rawB,
    const float* __restrict__ b1)
{
  __shared__ __align__(16) char smem[65536];
  const int cpx = gridDim.x >> 3;                             // 512/8 = 64
  const int virt = (blockIdx.x & 7) * cpx + (blockIdx.x >> 3);
  const int mb = (virt & 63) * 128;
  const int nb = (virt >> 6) * 128;
  gemm2_engine<3>(xbf, DIN, DIN, hbf, DH, BTcat, DIN + DH,
                  pre1, DH, rawB, b1, nullptr, mb, nb, DIN + DH, smem);
}

// ---- merged tail: blocks [0,768) G2 scales; [768,1024) GA rawA ----
__global__ __launch_bounds__(512, 4) void tail_gemm_k(
    const unsigned short* __restrict__ hbf,
    const unsigned short* __restrict__ Abf,
    const unsigned short* __restrict__ tbf,
    const unsigned short* __restrict__ W2T,
    unsigned short* __restrict__ rawA,
    unsigned short* __restrict__ scales,
    const float* __restrict__ b2,
    const float* __restrict__ base_tau)
{
  __shared__ __align__(16) char smem[65536];
  const int b = blockIdx.x;
  if (b < 768) {
    const int mb = (b & 63) * 128, nb = (b >> 6) * 128;      // N = 12*128 = 1536
    gemm2_engine<1>(tbf, DH, DH, nullptr, 0, W2T, DH,
                    scales, 3 * DH, nullptr, b2, base_tau, mb, nb, DH, smem);
  } else {
    const int b2i = b - 768;
    const int mb = (b2i & 63) * 128, nb = (b2i >> 6) * 128;  // N = 4*128 = 512
    gemm2_engine<2>(hbf, DH, DH, nullptr, 0, Abf, DH,
                    rawA, DH, nullptr, nullptr, nullptr, mb, nb, DH, smem);
  }
}

// ---------- block-wide sum over 256 threads (4 waves) ----------
__device__ __forceinline__ float block_sum256(float v, float* red) {
#pragma unroll
  for (int m = 32; m >= 1; m >>= 1) v += __shfl_xor(v, m, 64);
  __syncthreads();
  if ((threadIdx.x & 63) == 0) red[threadIdx.x >> 6] = v;
  __syncthreads();
  return red[0] + red[1] + red[2] + red[3];
}

// ---------- t = bf16(gelu_exact(LN(pre1))) ----------
__global__ __launch_bounds__(256) void ln_gelu_k(
    const unsigned short* __restrict__ pre,
    const float* __restrict__ g, const float* __restrict__ b,
    unsigned short* __restrict__ t)
{
  __shared__ float red[4];
  const int row = blockIdx.x;
  const int c = threadIdx.x * 2;
  const size_t ro = (size_t)row * DH;
  u16x2 raw = *(const u16x2*)(pre + ro + c);
  const float v0 = bf2f(raw[0]), v1 = bf2f(raw[1]);
  const float mu = block_sum256(v0 + v1, red) * (1.0f / DH);
  const float d0 = v0 - mu, d1 = v1 - mu;
  const float var = block_sum256(d0 * d0 + d1 * d1, red) * (1.0f / DH);
  const float inv = rsqrtf(var + 1e-5f);
  const float y0 = d0 * inv * g[c] + b[c];
  const float y1 = d1 * inv * g[c + 1] + b[c + 1];
  u16x2 o = { f2bf(0.5f * y0 * (1.0f + erff(y0 * 0.70710678118f))),
              f2bf(0.5f * y1 * (1.0f + erff(y1 * 0.70710678118f))) };
  *(u16x2*)(t + ro + c) = o;
}

// ---------- new_h = LN(h + dt*(-h*tauinv + tanh(rawA*arow + rawB*bcol))) ----------
__global__ __launch_bounds__(256) void final_k(
    const float* __restrict__ h,
    const unsigned short* __restrict__ rawA,
    const unsigned short* __restrict__ rawB,
    const unsigned short* __restrict__ scales,
    const float* __restrict__ hn_g, const float* __restrict__ hn_b,
    float* __restrict__ out)
{
  __shared__ float red[4];
  const int row = blockIdx.x;
  const int c = threadIdx.x * 2;
  const size_t ro = (size_t)row * DH;
  f32x2 hv = *(const f32x2*)(h + ro + c);
  u16x2 ra = *(const u16x2*)(rawA + ro + c);
  u16x2 rb = *(const u16x2*)(rawB + ro + c);
  const unsigned short* sc = scales + (size_t)row * (3 * DH);
  u16x2 ti  = *(const u16x2*)(sc + c);
  u16x2 arw = *(const u16x2*)(sc + DH + c);
  u16x2 bcl = *(const u16x2*)(sc + 2 * DH + c);
  const float u0 = hv[0] + 0.1f * (-hv[0] * bf2f(ti[0])
                 + tanhf(bf2f(ra[0]) * bf2f(arw[0]) + bf2f(rb[0]) * bf2f(bcl[0])));
  const float u1 = hv[1] + 0.1f * (-hv[1] * bf2f(ti[1])
                 + tanhf(bf2f(ra[1]) * bf2f(arw[1]) + bf2f(rb[1]) * bf2f(bcl[1])));
  const float mu = block_sum256(u0 + u1, red) * (1.0f / DH);
  const float d0 = u0 - mu, d1 = u1 - mu;
  const float var = block_sum256(d0 * d0 + d1 * d1, red) * (1.0f / DH);
  const float inv = rsqrtf(var + 1e-5f);
  f32x2 o = { d0 * inv * hn_g[c] + hn_b[c],
              d1 * inv * hn_g[c + 1] + hn_b[c + 1] };
  *(f32x2*)(out + ro + c) = o;
}

extern "C" void kernel_launch(void* const* d_in, const int* in_sizes, int n_in,
                              void* d_out, int out_size, void* d_ws, size_t ws_size,
                              hipStream_t stream)
{
  const float* x        = (const float*)d_in[0];
  const float* h        = (const float*)d_in[1];
  const float* W1       = (const float*)d_in[2];   // [4608][512]
  const float* b1       = (const float*)d_in[3];
  const float* ln1_g    = (const float*)d_in[4];
  const float* ln1_b    = (const float*)d_in[5];
  const float* W2       = (const float*)d_in[6];   // [512][1536]
  const float* b2       = (const float*)d_in[7];
  const float* base_tau = (const float*)d_in[8];
  const float* base_A   = (const float*)d_in[9];   // [512][512]
  const float* base_B   = (const float*)d_in[10];  // [4096][512]
  const float* hn_g     = (const float*)d_in[11];
  const float* hn_b     = (const float*)d_in[12];

  char* w = (char*)d_ws;
  // ws layout (bytes), total 128,974,848 (== proven-safe footprint):
  unsigned short* xbf    = (unsigned short*)(w);               // [8192][4096] 67,108,864
  unsigned short* hbf    = (unsigned short*)(w + 67108864);    // [8192][512]   8,388,608
  unsigned short* BTcat  = (unsigned short*)(w + 75497472);    // [1024][4608]  9,437,184
  unsigned short* tbf    = (unsigned short*)(w + 75497472);    // ALIAS over BTcat (dead after fused GEMM)
  unsigned short* W2T    = (unsigned short*)(w + 84934656);    // [1536][512]   1,572,864
  unsigned short* Abf    = (unsigned short*)(w + 86507520);    // [512][512]      524,288
  unsigned short* pre1   = (unsigned short*)(w + 87031808);    // [8192][512]   8,388,608
  unsigned short* rawA   = (unsigned short*)(w + 87031808);    // ALIAS over pre1 (dead after ln_gelu)
  unsigned short* rawB   = (unsigned short*)(w + 95420416);    // [8192][512]   8,388,608
  unsigned short* scales = (unsigned short*)(w + 103809024);   // [8192][1536] 25,165,824

  // ---- single prep dispatch: all casts + transposes ----
  prep_all_k<<<42368, 256, 0, stream>>>(x, xbf, h, hbf, base_A, Abf,
                                        W1, base_B, BTcat, W2, W2T);

  // ---- fused G1|GB -> pre1, rawB ----
  fused_gemm_k<<<512, 512, 0, stream>>>(xbf, hbf, BTcat, pre1, rawB, b1);
  // ---- t = gelu(LN(pre1)) -> tbf ----
  ln_gelu_k<<<BATCH, 256, 0, stream>>>(pre1, ln1_g, ln1_b, tbf);
  // ---- merged tail: scales = transforms(t @ W2 + b2); rawA = h @ base_A^T ----
  tail_gemm_k<<<1024, 512, 0, stream>>>(hbf, Abf, tbf, W2T, rawA, scales, b2, base_tau);
  // ---- final: dhdt + LN -> f32 out ----
  final_k<<<BATCH, 256, 0, stream>>>(h, rawA, rawB, scales, hn_g, hn_b, (float*)d_out);
}

// Round 10
// 213.120 us; speedup vs baseline: 4.3012x; 1.0128x over previous
//
#include <hip/hip_runtime.h>

#define BATCH 8192
#define DIN 4096
#define DH 512

typedef float f32x4 __attribute__((ext_vector_type(4)));
typedef float f32x2 __attribute__((ext_vector_type(2)));
typedef short s16x8 __attribute__((ext_vector_type(8)));
typedef unsigned short u16x2 __attribute__((ext_vector_type(2)));
typedef unsigned short u16x4 __attribute__((ext_vector_type(4)));
typedef unsigned short u16x8 __attribute__((ext_vector_type(8)));

// round-to-nearest-even f32 -> bf16 bits
static __device__ __forceinline__ unsigned short f2bf(float f) {
  unsigned int u = __float_as_uint(f);
  u += 0x7FFFu + ((u >> 16) & 1u);
  return (unsigned short)(u >> 16);
}
static __device__ __forceinline__ float bf2f(unsigned short s) {
  return __uint_as_float(((unsigned int)s) << 16);
}

typedef const __attribute__((address_space(1))) unsigned int* gas_ptr;
typedef __attribute__((address_space(3))) unsigned int* las_ptr;
// async global->LDS, 16B per lane; LDS dest = wave-uniform base + lane*16
static __device__ __forceinline__ void gl_lds16(const unsigned short* g, unsigned short* l) {
  __builtin_amdgcn_global_load_lds((gas_ptr)g, (las_ptr)l, 16, 0, 0);
}

// ---------- transpose tile body: in f32 [R][C] -> out bf16 [(row_off+c)][r] ----------
static __device__ __forceinline__ void transpose_body(
    const float* __restrict__ in, int C,
    unsigned short* __restrict__ out, int ldo, int row_off,
    int bx, int by, float (*tl)[33])
{
  const int tid = threadIdx.x;
  const int tx = tid & 31, ty = tid >> 5;
  const int c0 = bx * 32, r0 = by * 32;
#pragma unroll
  for (int i = 0; i < 4; i++)
    tl[ty + 8 * i][tx] = in[(size_t)(r0 + ty + 8 * i) * C + c0 + tx];
  __syncthreads();
#pragma unroll
  for (int i = 0; i < 4; i++)
    out[(size_t)(row_off + c0 + ty + 8 * i) * ldo + r0 + tx] = f2bf(tl[tx][ty + 8 * i]);
}

// ---------- single prep dispatch: cast x | cast h | cast A | T(W1) | T(base_B) | zfill | T(W2) ----------
__global__ __launch_bounds__(256) void prep_all_k(
    const float* __restrict__ x, unsigned short* __restrict__ xbf,
    const float* __restrict__ h, unsigned short* __restrict__ hbf,
    const float* __restrict__ base_A, unsigned short* __restrict__ Abf,
    const float* __restrict__ W1, const float* __restrict__ base_B,
    unsigned short* __restrict__ BTcat,
    const float* __restrict__ W2, unsigned short* __restrict__ W2T)
{
  __shared__ float tl[32][33];
  const int b = blockIdx.x;
  const int tid = threadIdx.x;
  const int KC = DIN + DH;
  if (b < 32768) {
    const int i = (b * 256 + tid) * 4;
    f32x4 v = *(const f32x4*)(x + i);
    u16x4 p = { f2bf(v[0]), f2bf(v[1]), f2bf(v[2]), f2bf(v[3]) };
    *(u16x4*)(xbf + i) = p;
  } else if (b < 36864) {
    const int i = ((b - 32768) * 256 + tid) * 4;
    f32x4 v = *(const f32x4*)(h + i);
    u16x4 p = { f2bf(v[0]), f2bf(v[1]), f2bf(v[2]), f2bf(v[3]) };
    *(u16x4*)(hbf + i) = p;
  } else if (b < 37120) {
    const int i = ((b - 36864) * 256 + tid) * 4;
    f32x4 v = *(const f32x4*)(base_A + i);
    u16x4 p = { f2bf(v[0]), f2bf(v[1]), f2bf(v[2]), f2bf(v[3]) };
    *(u16x4*)(Abf + i) = p;
  } else if (b < 39424) {
    const int bb = b - 37120;                      // W1 [4608][512]
    transpose_body(W1, DH, BTcat, KC, 0, bb & 15, bb >> 4, tl);
  } else if (b < 41472) {
    const int bb = b - 39424;                      // base_B [4096][512]
    transpose_body(base_B, DH, BTcat, KC, DH, bb & 15, bb >> 4, tl);
  } else if (b < 41600) {
    const int gid = (b - 41472) * 256 + tid;       // zero pad corner 512x512
    const int row = gid >> 6, c = (gid & 63) * 8;
    u16x8 z = { 0, 0, 0, 0, 0, 0, 0, 0 };
    *(u16x8*)(BTcat + (size_t)(DH + row) * KC + DIN + c) = z;
  } else {
    const int bb = b - 41600;                      // W2 [512][1536]
    transpose_body(W2, 3 * DH, W2T, DH, 0, bb % 48, bb / 48, tl);
  }
}

// ---------------------------------------------------------------------------
// Dual-K-stream GEMM engine, 4-phase-lite schedule (T3-lite + T5).
// 128x128 tile, 512 threads = 8 waves in 2 groups; group g computes K-tiles
// 2t+g; each group's 4 waves own 64x64 sub-tiles (4x4 frags of 16x16x32).
// Per-group double-buffered LDS (64KB total). Per period (one K-tile/group):
//   pre-read af[0..3], bv[0]
//   phase p=0..3: { read bv[p+1] | STAGE_A@p0 / STAGE_B@p1 | setprio(1),
//                   4 MFMA(af[*],bv[p]), setprio(0) | s_barrier }
//   final phase: lgkmcnt(0)+vmcnt(0)+sched_barrier(0) before barrier
//   (rule #18: prevents MFMA sink past barrier -> gl_lds overwrite race).
// Compiler auto-emits counted lgkm for ds->MFMA deps (bv prefetched 1 phase
// ahead). Swizzle (0-conflict, r7): scol=((l&3)^((l>>3)&3))*8,
// fk=((l>>4)^((l>>1)&3))*8.
// Epilogue: group 1 dumps f32 accs to LDS, group 0 adds and writes C.
// EPI: 1 = +bias then scale transforms -> C0; 2 = raw -> C0;
//      3 = split: col<512 -> C0 +bias ; col>=512 -> C1 raw (both ld 512).
// ---------------------------------------------------------------------------
template<int EPI>
static __device__ __forceinline__ void gemm2_engine(
    const unsigned short* __restrict__ A0, int lda0, int K0,
    const unsigned short* __restrict__ A1, int lda1,
    const unsigned short* __restrict__ BT, int ldb,
    unsigned short* __restrict__ C0, int ldc,
    unsigned short* __restrict__ C1,
    const float* __restrict__ bias,
    const float* __restrict__ base_tau,
    int mb, int nb, int K, char* smem)
{
  unsigned short* As = (unsigned short*)smem;             // [grp][buf][4096]
  unsigned short* Bs = (unsigned short*)(smem + 32768);   // [grp][buf][4096]
  float* red = (float*)smem;                              // 64KB reduction (reuse)

  const int tid = threadIdx.x;
  const int lane = tid & 63;
  const int wid = tid >> 6;        // 0..7
  const int grp = wid >> 2;        // 0 = even K-tiles, 1 = odd
  const int wg  = wid & 3;         // wave within group
  const int wm = (wg >> 1) * 64;
  const int wn = (wg & 1) * 64;
  const int srow = lane >> 2;                                // staging row in 16-chunk
  const int scol = ((lane & 3) ^ ((lane >> 3) & 3)) * 8;     // swizzled source chunk
  const int fr = lane & 15;                                  // fragment row/col
  const int fk = ((lane >> 4) ^ ((lane >> 1) & 3)) * 8;      // swizzled read chunk
  const int NT2 = K / 64;          // periods (2 K-tiles consumed per period)

  f32x4 acc[4][4];
#pragma unroll
  for (int i = 0; i < 4; i++)
#pragma unroll
    for (int j = 0; j < 4; j++)
      acc[i][j] = (f32x4){ 0.f, 0.f, 0.f, 0.f };

  // stage this group's A-half / B-half for period 'per' into buffer buf
  auto STAGE_A = [&](int buf, int per) {
    const int tk = 2 * per + grp;
    const int k0 = tk * 32;
    const bool s0 = (k0 < K0);
    const unsigned short* Ab = s0 ? A0 : A1;
    const int ld = s0 ? lda0 : lda1;
    const int ko = (s0 ? k0 : k0 - K0) + scol;
    unsigned short* ab = As + (grp * 2 + buf) * 4096 + (32 * wg) * 32;
#pragma unroll
    for (int c = 0; c < 2; c++) {
      const int r = 32 * wg + c * 16 + srow;
      gl_lds16(Ab + (size_t)(mb + r) * ld + ko, ab + c * 16 * 32);
    }
  };
  auto STAGE_B = [&](int buf, int per) {
    const int tk = 2 * per + grp;
    const int k0 = tk * 32;
    unsigned short* bb = Bs + (grp * 2 + buf) * 4096 + (32 * wg) * 32;
#pragma unroll
    for (int c = 0; c < 2; c++) {
      const int r = 32 * wg + c * 16 + srow;
      gl_lds16(BT + (size_t)(nb + r) * ldb + k0 + scol, bb + c * 16 * 32);
    }
  };

  STAGE_A(0, 0);
  STAGE_B(0, 0);
  asm volatile("s_waitcnt vmcnt(0)" ::: "memory");
  __builtin_amdgcn_s_barrier();

  int buf = 0;
  for (int t = 0; t < NT2; t++) {
    const unsigned short* ar = As + (grp * 2 + buf) * 4096;
    const unsigned short* br = Bs + (grp * 2 + buf) * 4096;
    s16x8 af[4], bv[4];
#pragma unroll
    for (int mi = 0; mi < 4; mi++)
      af[mi] = *(const s16x8*)(ar + (wm + mi * 16 + fr) * 32 + fk);
    bv[0] = *(const s16x8*)(br + (wn + fr) * 32 + fk);

#pragma unroll
    for (int p = 0; p < 4; p++) {
      if (p < 3)
        bv[p + 1] = *(const s16x8*)(br + (wn + (p + 1) * 16 + fr) * 32 + fk);
      if (p == 0 && t + 1 < NT2) STAGE_A(buf ^ 1, t + 1);
      if (p == 1 && t + 1 < NT2) STAGE_B(buf ^ 1, t + 1);

      __builtin_amdgcn_s_setprio(1);
#pragma unroll
      for (int mi = 0; mi < 4; mi++)
        acc[mi][p] = __builtin_amdgcn_mfma_f32_16x16x32_bf16(
            af[mi], bv[p], acc[mi][p], 0, 0, 0);
      __builtin_amdgcn_s_setprio(0);

      if (p == 3) {
        // period-final gate: all ds_reads of buf drained + this period's
        // staged loads landed, and nothing crosses the barrier (rule #18)
        asm volatile("s_waitcnt vmcnt(0) lgkmcnt(0)" ::: "memory");
        __builtin_amdgcn_sched_barrier(0);
      }
      __builtin_amdgcn_s_barrier();
    }
    buf ^= 1;
  }

  // ---- cross-group reduction: group1 -> LDS, group0 adds ----
  if (grp == 1) {
#pragma unroll
    for (int mi = 0; mi < 4; mi++)
#pragma unroll
      for (int ni = 0; ni < 4; ni++)
        *(f32x4*)(red + (((wg * 4 + mi) * 4 + ni) * 64 + lane) * 4) = acc[mi][ni];
  }
  __syncthreads();
  if (grp != 0) return;

  const int rb = (lane >> 4) * 4;
#pragma unroll
  for (int mi = 0; mi < 4; mi++) {
#pragma unroll
    for (int ni = 0; ni < 4; ni++) {
      f32x4 o = *(const f32x4*)(red + (((wg * 4 + mi) * 4 + ni) * 64 + lane) * 4);
      acc[mi][ni] += o;
#pragma unroll
      for (int r = 0; r < 4; r++) {
        const int row = mb + wm + mi * 16 + rb + r;
        const int col = nb + wn + ni * 16 + fr;
        float v = acc[mi][ni][r];
        if (EPI == 3) {
          if (col < DH) C0[(size_t)row * DH + col] = f2bf(v + bias[col]);
          else          C1[(size_t)row * DH + (col - DH)] = f2bf(v);
        } else if (EPI == 2) {
          C0[(size_t)row * ldc + col] = f2bf(v);
        } else if (EPI == 1) {
          v += bias[col];
          if ((col >> 9) == 0) {
            const float s = 1.0f / (1.0f + expf(-v));
            v = 1.0f / (base_tau[col & (DH - 1)] * 2.0f * s + 1e-8f);  // tau_inv
          } else {
            v = 1.0f + 0.5f * tanhf(v);                                 // A_row/B_col
          }
          C0[(size_t)row * ldc + col] = f2bf(v);
        }
      }
    }
  }
}

// ---- fused G1|GB: [x|h] @ [W1 | base_B~] -> pre1, rawB. XCD-swizzled ----
__global__ __launch_bounds__(512, 4) void fused_gemm_k(
    const unsigned short* __restrict__ xbf,
    const unsigned short* __restrict__ hbf,
    const unsigned short* __restrict__ BTcat,
    unsigned short* __restrict__ pre1,
    unsigned short* __restrict__ rawB,
    const float* __restrict__ b1)
{
  __shared__ __align__(16) char smem[65536];
  const int cpx = gridDim.x >> 3;                             // 512/8 = 64
  const int virt = (blockIdx.x & 7) * cpx + (blockIdx.x >> 3);
  const int mb = (virt & 63) * 128;
  const int nb = (virt >> 6) * 128;
  gemm2_engine<3>(xbf, DIN, DIN, hbf, DH, BTcat, DIN + DH,
                  pre1, DH, rawB, b1, nullptr, mb, nb, DIN + DH, smem);
}

// ---- merged tail: blocks [0,768) G2 scales; [768,1024) GA rawA ----
__global__ __launch_bounds__(512, 4) void tail_gemm_k(
    const unsigned short* __restrict__ hbf,
    const unsigned short* __restrict__ Abf,
    const unsigned short* __restrict__ tbf,
    const unsigned short* __restrict__ W2T,
    unsigned short* __restrict__ rawA,
    unsigned short* __restrict__ scales,
    const float* __restrict__ b2,
    const float* __restrict__ base_tau)
{
  __shared__ __align__(16) char smem[65536];
  const int b = blockIdx.x;
  if (b < 768) {
    const int mb = (b & 63) * 128, nb = (b >> 6) * 128;      // N = 12*128 = 1536
    gemm2_engine<1>(tbf, DH, DH, nullptr, 0, W2T, DH,
                    scales, 3 * DH, nullptr, b2, base_tau, mb, nb, DH, smem);
  } else {
    const int b2i = b - 768;
    const int mb = (b2i & 63) * 128, nb = (b2i >> 6) * 128;  // N = 4*128 = 512
    gemm2_engine<2>(hbf, DH, DH, nullptr, 0, Abf, DH,
                    rawA, DH, nullptr, nullptr, nullptr, mb, nb, DH, smem);
  }
}

// ---------- block-wide sum over 256 threads (4 waves) ----------
__device__ __forceinline__ float block_sum256(float v, float* red) {
#pragma unroll
  for (int m = 32; m >= 1; m >>= 1) v += __shfl_xor(v, m, 64);
  __syncthreads();
  if ((threadIdx.x & 63) == 0) red[threadIdx.x >> 6] = v;
  __syncthreads();
  return red[0] + red[1] + red[2] + red[3];
}

// ---------- t = bf16(gelu_exact(LN(pre1))) ----------
__global__ __launch_bounds__(256) void ln_gelu_k(
    const unsigned short* __restrict__ pre,
    const float* __restrict__ g, const float* __restrict__ b,
    unsigned short* __restrict__ t)
{
  __shared__ float red[4];
  const int row = blockIdx.x;
  const int c = threadIdx.x * 2;
  const size_t ro = (size_t)row * DH;
  u16x2 raw = *(const u16x2*)(pre + ro + c);
  const float v0 = bf2f(raw[0]), v1 = bf2f(raw[1]);
  const float mu = block_sum256(v0 + v1, red) * (1.0f / DH);
  const float d0 = v0 - mu, d1 = v1 - mu;
  const float var = block_sum256(d0 * d0 + d1 * d1, red) * (1.0f / DH);
  const float inv = rsqrtf(var + 1e-5f);
  const float y0 = d0 * inv * g[c] + b[c];
  const float y1 = d1 * inv * g[c + 1] + b[c + 1];
  u16x2 o = { f2bf(0.5f * y0 * (1.0f + erff(y0 * 0.70710678118f))),
              f2bf(0.5f * y1 * (1.0f + erff(y1 * 0.70710678118f))) };
  *(u16x2*)(t + ro + c) = o;
}

// ---------- new_h = LN(h + dt*(-h*tauinv + tanh(rawA*arow + rawB*bcol))) ----------
__global__ __launch_bounds__(256) void final_k(
    const float* __restrict__ h,
    const unsigned short* __restrict__ rawA,
    const unsigned short* __restrict__ rawB,
    const unsigned short* __restrict__ scales,
    const float* __restrict__ hn_g, const float* __restrict__ hn_b,
    float* __restrict__ out)
{
  __shared__ float red[4];
  const int row = blockIdx.x;
  const int c = threadIdx.x * 2;
  const size_t ro = (size_t)row * DH;
  f32x2 hv = *(const f32x2*)(h + ro + c);
  u16x2 ra = *(const u16x2*)(rawA + ro + c);
  u16x2 rb = *(const u16x2*)(rawB + ro + c);
  const unsigned short* sc = scales + (size_t)row * (3 * DH);
  u16x2 ti  = *(const u16x2*)(sc + c);
  u16x2 arw = *(const u16x2*)(sc + DH + c);
  u16x2 bcl = *(const u16x2*)(sc + 2 * DH + c);
  const float u0 = hv[0] + 0.1f * (-hv[0] * bf2f(ti[0])
                 + tanhf(bf2f(ra[0]) * bf2f(arw[0]) + bf2f(rb[0]) * bf2f(bcl[0])));
  const float u1 = hv[1] + 0.1f * (-hv[1] * bf2f(ti[1])
                 + tanhf(bf2f(ra[1]) * bf2f(arw[1]) + bf2f(rb[1]) * bf2f(bcl[1])));
  const float mu = block_sum256(u0 + u1, red) * (1.0f / DH);
  const float d0 = u0 - mu, d1 = u1 - mu;
  const float var = block_sum256(d0 * d0 + d1 * d1, red) * (1.0f / DH);
  const float inv = rsqrtf(var + 1e-5f);
  f32x2 o = { d0 * inv * hn_g[c] + hn_b[c],
              d1 * inv * hn_g[c + 1] + hn_b[c + 1] };
  *(f32x2*)(out + ro + c) = o;
}

extern "C" void kernel_launch(void* const* d_in, const int* in_sizes, int n_in,
                              void* d_out, int out_size, void* d_ws, size_t ws_size,
                              hipStream_t stream)
{
  const float* x        = (const float*)d_in[0];
  const float* h        = (const float*)d_in[1];
  const float* W1       = (const float*)d_in[2];   // [4608][512]
  const float* b1       = (const float*)d_in[3];
  const float* ln1_g    = (const float*)d_in[4];
  const float* ln1_b    = (const float*)d_in[5];
  const float* W2       = (const float*)d_in[6];   // [512][1536]
  const float* b2       = (const float*)d_in[7];
  const float* base_tau = (const float*)d_in[8];
  const float* base_A   = (const float*)d_in[9];   // [512][512]
  const float* base_B   = (const float*)d_in[10];  // [4096][512]
  const float* hn_g     = (const float*)d_in[11];
  const float* hn_b     = (const float*)d_in[12];

  char* w = (char*)d_ws;
  // ws layout (bytes), total 128,974,848 (== proven-safe footprint):
  unsigned short* xbf    = (unsigned short*)(w);               // [8192][4096] 67,108,864
  unsigned short* hbf    = (unsigned short*)(w + 67108864);    // [8192][512]   8,388,608
  unsigned short* BTcat  = (unsigned short*)(w + 75497472);    // [1024][4608]  9,437,184
  unsigned short* tbf    = (unsigned short*)(w + 75497472);    // ALIAS over BTcat (dead after fused GEMM)
  unsigned short* W2T    = (unsigned short*)(w + 84934656);    // [1536][512]   1,572,864
  unsigned short* Abf    = (unsigned short*)(w + 86507520);    // [512][512]      524,288
  unsigned short* pre1   = (unsigned short*)(w + 87031808);    // [8192][512]   8,388,608
  unsigned short* rawA   = (unsigned short*)(w + 87031808);    // ALIAS over pre1 (dead after ln_gelu)
  unsigned short* rawB   = (unsigned short*)(w + 95420416);    // [8192][512]   8,388,608
  unsigned short* scales = (unsigned short*)(w + 103809024);   // [8192][1536] 25,165,824

  // ---- single prep dispatch: all casts + transposes ----
  prep_all_k<<<42368, 256, 0, stream>>>(x, xbf, h, hbf, base_A, Abf,
                                        W1, base_B, BTcat, W2, W2T);

  // ---- fused G1|GB -> pre1, rawB ----
  fused_gemm_k<<<512, 512, 0, stream>>>(xbf, hbf, BTcat, pre1, rawB, b1);
  // ---- t = gelu(LN(pre1)) -> tbf ----
  ln_gelu_k<<<BATCH, 256, 0, stream>>>(pre1, ln1_g, ln1_b, tbf);
  // ---- merged tail: scales = transforms(t @ W2 + b2); rawA = h @ base_A^T ----
  tail_gemm_k<<<1024, 512, 0, stream>>>(hbf, Abf, tbf, W2T, rawA, scales, b2, base_tau);
  // ---- final: dhdt + LN -> f32 out ----
  final_k<<<BATCH, 256, 0, stream>>>(h, rawA, rawB, scales, hn_g, hn_b, (float*)d_out);
}